// Round 4
// baseline (4280.944 us; speedup 1.0000x reference)
//
#include <hip/hip_runtime.h>

#define Tn 512
#define Bn 64
#define In 128
#define Hn 1024
#define GBn 16    // batch rows per group
#define NGn 4     // independent batch groups
#define NBLKn 32  // blocks per group
#define NCOLn 32  // H columns per block

typedef __attribute__((ext_vector_type(8))) short short8;
typedef __attribute__((ext_vector_type(4))) float f32x4;
typedef unsigned long long u64;

__device__ __forceinline__ short f2bf(float f) {
  unsigned u = __builtin_bit_cast(unsigned, f);
  unsigned r = u + 0x7FFFu + ((u >> 16) & 1u);  // RTNE
  return (short)(r >> 16);
}
__device__ __forceinline__ float sigm(float x) { return 1.f / (1.f + __expf(-x)); }
__device__ __forceinline__ float tanh_f(float x) {
  float ax = fabsf(x);
  float e = __expf(-2.f * ax);
  float t = (1.f - e) / (1.f + e);
  return x < 0.f ? -t : t;
}
__device__ __forceinline__ short8 cvt8(const float* p) {
  float4 a0 = *(const float4*)p;
  float4 a1 = *(const float4*)(p + 4);
  short8 w;
  w[0] = f2bf(a0.x); w[1] = f2bf(a0.y); w[2] = f2bf(a0.z); w[3] = f2bf(a0.w);
  w[4] = f2bf(a1.x); w[5] = f2bf(a1.y); w[6] = f2bf(a1.z); w[7] = f2bf(a1.w);
  return w;
}

// f32 -> bf16 bits, 8 per thread. Grid must cover n/8 exactly.
__global__ void __launch_bounds__(256) cvt_kernel(const float* __restrict__ x,
                                                  unsigned short* __restrict__ xb) {
  size_t idx = ((size_t)blockIdx.x * 256 + threadIdx.x) * 8;
  *(short8*)(xb + idx) = cvt8(x + idx);
}

// pp word format: (bf16(h) << 16) | tag, tag = t+1 (memset-0 never matches).
// Slot parity t&1; consumer at step t polls tag==t on slot (t-1)&1.
// Safety: producer's tag-t words are data-dependent on its step-(t-1) reads
// of slot t&1, so tag-t visible => that producer finished reading the slot
// it is about to overwrite. 2 slots suffice; no fences, no acks, no flags.
__global__ void __launch_bounds__(256, 1) lstm_kernel(
    const unsigned short* __restrict__ xb, const float* __restrict__ W_ih,
    const float* __restrict__ W_hh, const float* __restrict__ b_ih,
    const float* __restrict__ b_hh, unsigned short* __restrict__ hsb,
    unsigned* __restrict__ pp) {
  const int bid = blockIdx.x;
  const int grp = bid >> 5;   // batch group 0..3
  const int hc = bid & 31;    // H-chunk 0..31 (32 cols each)
  const int wid = threadIdx.x >> 6;  // wave = gate (i,f,g,o)
  const int lane = threadIdx.x & 63;
  const int rowsel = lane & 15;
  const int k8 = (lane >> 4) * 8;

  __shared__ unsigned short h_lds[GBn * Hn];  // 32 KB staged h (swizzled)
  __shared__ float gates_s[4][16][33];        // padded vs bank conflicts
  __shared__ float bias_s[4][NCOLn];

  if (threadIdx.x < 128) {
    int gg = threadIdx.x >> 5, cc = threadIdx.x & 31;
    int idx = gg * Hn + hc * NCOLn + cc;
    bias_s[gg][cc] = b_ih[idx] + b_hh[idx];
  }

  // --- weights -> registers (B-fragments for 2 col-tiles). One-time. ---
  const int wr0 = wid * Hn + hc * NCOLn + rowsel;  // tile0 gate-row
  const int wr1 = wr0 + 16;                        // tile1 gate-row
  short8 whh0[32], whh1[32], wih0[4], wih1[4];
#pragma unroll
  for (int kt = 0; kt < 32; ++kt) {
    whh0[kt] = cvt8(W_hh + (size_t)wr0 * Hn + kt * 32 + k8);
    whh1[kt] = cvt8(W_hh + (size_t)wr1 * Hn + kt * 32 + k8);
  }
#pragma unroll
  for (int kt = 0; kt < 4; ++kt) {
    wih0[kt] = cvt8(W_ih + (size_t)wr0 * In + kt * 32 + k8);
    wih1[kt] = cvt8(W_ih + (size_t)wr1 * In + kt * 32 + k8);
  }
  __syncthreads();

  unsigned* ppg = pp + (size_t)grp * 2 * GBn * Hn;
  const unsigned short* xrow = xb + (size_t)(grp * GBn + rowsel) * (Tn * In);

  const int prow = threadIdx.x >> 4;        // pointwise row 0..15
  const int pc2 = (threadIdx.x & 15) * 2;   // pointwise col pair
  float c0r = 0.f, c1r = 0.f;

  // LDS fragment-read base (bytes) + swizzle
  const int rswz = (rowsel & 7) << 4;
  const int rbase = rowsel * 2048 + k8 * 2;
  // cooperative-load mapping: wave covers rows wid*4..wid*4+3
  const int ldrow = wid * 4 + (lane >> 4);
  const int ldcol = lane & 15;  // 64-word column group

#pragma clang loop unroll(disable)
  for (int t = 0; t < Tn; ++t) {
    f32x4 acc0[2], acc1[2];
#pragma unroll
    for (int q = 0; q < 2; ++q) {
      acc0[q] = (f32x4){0.f, 0.f, 0.f, 0.f};
      acc1[q] = (f32x4){0.f, 0.f, 0.f, 0.f};
    }

    // x-part: independent of h
    {
      const unsigned short* xp = xrow + (size_t)t * In + k8;
#pragma unroll
      for (int kt = 0; kt < 4; ++kt) {
        short8 a = *(const short8*)(xp + kt * 32);
        acc0[kt & 1] = __builtin_amdgcn_mfma_f32_16x16x32_bf16(a, wih0[kt],
                                                               acc0[kt & 1], 0, 0, 0);
        acc1[kt & 1] = __builtin_amdgcn_mfma_f32_16x16x32_bf16(a, wih1[kt],
                                                               acc1[kt & 1], 0, 0, 0);
      }
    }

    if (t > 0) {
      const u64 want2 = (u64)t | ((u64)t << 32);
      u64* src = (u64*)(ppg + ((t - 1) & 1) * (GBn * Hn));
      u64* pl = src + ldrow * 512 + ldcol * 32;
      // poll-the-data: two halves of 16 u64 (keeps VGPR pressure bounded);
      // a word once tagged-t is final, so committed halves never re-polled
#pragma unroll
      for (int half = 0; half < 2; ++half) {
        u64 v[16];
        while (true) {
          bool okv = true;
#pragma unroll
          for (int j = 0; j < 16; ++j)
            v[j] = __hip_atomic_load(pl + half * 16 + j, __ATOMIC_RELAXED,
                                     __HIP_MEMORY_SCOPE_AGENT);
#pragma unroll
          for (int j = 0; j < 16; ++j)
            okv = okv && ((v[j] & 0x0000FFFF0000FFFFULL) == want2);
          if (__all(okv)) break;
          __builtin_amdgcn_s_sleep(1);
        }
#pragma unroll
        for (int jj = 0; jj < 4; ++jj) {
          uint4 w;
          w.x = __builtin_amdgcn_perm((unsigned)(v[jj * 4 + 0] >> 32),
                                      (unsigned)v[jj * 4 + 0], 0x07060302);
          w.y = __builtin_amdgcn_perm((unsigned)(v[jj * 4 + 1] >> 32),
                                      (unsigned)v[jj * 4 + 1], 0x07060302);
          w.z = __builtin_amdgcn_perm((unsigned)(v[jj * 4 + 2] >> 32),
                                      (unsigned)v[jj * 4 + 2], 0x07060302);
          w.w = __builtin_amdgcn_perm((unsigned)(v[jj * 4 + 3] >> 32),
                                      (unsigned)v[jj * 4 + 3], 0x07060302);
          int byteoff = (ldrow * 2048 + ldcol * 128 + half * 64 + jj * 16) ^
                        ((ldrow & 7) << 4);
          *(uint4*)((char*)h_lds + byteoff) = w;
        }
      }
      __syncthreads();

      // h-part MFMAs from LDS (shared A-fragment across the two col-tiles)
#pragma unroll
      for (int kt = 0; kt < 32; ++kt) {
        short8 a = *(const short8*)((char*)h_lds + ((rbase + kt * 64) ^ rswz));
        acc0[kt & 1] = __builtin_amdgcn_mfma_f32_16x16x32_bf16(a, whh0[kt],
                                                               acc0[kt & 1], 0, 0, 0);
        acc1[kt & 1] = __builtin_amdgcn_mfma_f32_16x16x32_bf16(a, whh1[kt],
                                                               acc1[kt & 1], 0, 0, 0);
      }
    }

    f32x4 s0 = acc0[0] + acc0[1];
    f32x4 s1 = acc1[0] + acc1[1];
#pragma unroll
    for (int r = 0; r < 4; ++r) {
      gates_s[wid][(lane >> 4) * 4 + r][lane & 15] = s0[r];
      gates_s[wid][(lane >> 4) * 4 + r][16 + (lane & 15)] = s1[r];
    }
    __syncthreads();

    // pointwise: thread owns (prow, cols pc2, pc2+1); c stays in registers
    float i0 = gates_s[0][prow][pc2] + bias_s[0][pc2];
    float f0 = gates_s[1][prow][pc2] + bias_s[1][pc2];
    float g0 = gates_s[2][prow][pc2] + bias_s[2][pc2];
    float o0 = gates_s[3][prow][pc2] + bias_s[3][pc2];
    float i1 = gates_s[0][prow][pc2 + 1] + bias_s[0][pc2 + 1];
    float f1 = gates_s[1][prow][pc2 + 1] + bias_s[1][pc2 + 1];
    float g1 = gates_s[2][prow][pc2 + 1] + bias_s[2][pc2 + 1];
    float o1 = gates_s[3][prow][pc2 + 1] + bias_s[3][pc2 + 1];
    c0r = sigm(f0) * c0r + sigm(i0) * tanh_f(g0);
    c1r = sigm(f1) * c1r + sigm(i1) * tanh_f(g1);
    float h0 = sigm(o0) * tanh_f(c0r);
    float h1 = sigm(o1) * tanh_f(c1r);
    unsigned hb0 = (unsigned)(unsigned short)f2bf(h0);
    unsigned hb1 = (unsigned)(unsigned short)f2bf(h1);
    unsigned tag = (unsigned)(t + 1);
    u64 wv = (((u64)((hb1 << 16) | tag)) << 32) | (u64)((hb0 << 16) | tag);
    int wcol = hc * NCOLn + pc2;
    // fire-and-forget tagged store: no ack, no flag, no fence
    __hip_atomic_store((u64*)(ppg + (t & 1) * (GBn * Hn) + prow * Hn + wcol),
                       wv, __ATOMIC_RELAXED, __HIP_MEMORY_SCOPE_AGENT);
    *(unsigned*)(hsb + ((size_t)t * Bn + grp * GBn + prow) * Hn + wcol) =
        hb0 | (hb1 << 16);
  }
}

// out[b][t][i] = hs[row=t*64+b][:] . fcw_b16[i][:] + fcb[i], via MFMA.
__global__ void __launch_bounds__(256) fc_mfma_kernel(
    const unsigned short* __restrict__ hsb, const unsigned short* __restrict__ fwb,
    const float* __restrict__ fcb, float* __restrict__ out) {
  const int wid = threadIdx.x >> 6;
  const int lane = threadIdx.x & 63;
  const int rowsel = lane & 15;
  const int k8 = (lane >> 4) * 8;
  const int r0 = blockIdx.x * 16;
  const int i0 = wid * 32;
  f32x4 acc0 = {0.f, 0.f, 0.f, 0.f}, acc1 = {0.f, 0.f, 0.f, 0.f};
  const unsigned short* hrow = hsb + (size_t)(r0 + rowsel) * Hn + k8;
  const unsigned short* w0 = fwb + (size_t)(i0 + rowsel) * Hn + k8;
  const unsigned short* w1 = w0 + 16 * Hn;
#pragma unroll 8
  for (int kt = 0; kt < 32; ++kt) {
    short8 a = *(const short8*)(hrow + kt * 32);
    short8 b0 = *(const short8*)(w0 + kt * 32);
    short8 b1 = *(const short8*)(w1 + kt * 32);
    acc0 = __builtin_amdgcn_mfma_f32_16x16x32_bf16(a, b0, acc0, 0, 0, 0);
    acc1 = __builtin_amdgcn_mfma_f32_16x16x32_bf16(a, b1, acc1, 0, 0, 0);
  }
  const int n = lane & 15;
  float bias0 = fcb[i0 + n], bias1 = fcb[i0 + 16 + n];
#pragma unroll
  for (int r = 0; r < 4; ++r) {
    int row = r0 + (lane >> 4) * 4 + r;  // row = t*64 + b
    float* op = out + ((size_t)(row & 63) * Tn + (row >> 6)) * In;
    op[i0 + n] = acc0[r] + bias0;
    op[i0 + 16 + n] = acc1[r] + bias1;
  }
}

extern "C" void kernel_launch(void* const* d_in, const int* in_sizes, int n_in,
                              void* d_out, int out_size, void* d_ws,
                              size_t ws_size, hipStream_t stream) {
  const float* x    = (const float*)d_in[0];
  const float* W_ih = (const float*)d_in[1];
  const float* W_hh = (const float*)d_in[2];
  const float* b_ih = (const float*)d_in[3];
  const float* b_hh = (const float*)d_in[4];
  const float* fc_w = (const float*)d_in[5];
  const float* fc_b = (const float*)d_in[6];
  float* out = (float*)d_out;

  const size_t hs_b = (size_t)Tn * Bn * Hn * 2;        // 64 MiB bf16 hs
  const size_t x_b  = (size_t)Bn * Tn * In * 2;        // 8 MiB bf16 x
  const size_t fw_b = (size_t)In * Hn * 2;             // 256 KiB bf16 fc_w
  const size_t pp_b = (size_t)NGn * 2 * GBn * Hn * 4;  // 512 KiB tagged u32

  char* wsc = (char*)d_ws;
  unsigned short* hsb = (unsigned short*)wsc;
  unsigned short* xb  = (unsigned short*)(wsc + hs_b);
  unsigned short* fwb = (unsigned short*)(wsc + hs_b + x_b);
  unsigned* pp = (unsigned*)(wsc + hs_b + x_b + fw_b);

  (void)hipMemsetAsync(pp, 0, pp_b, stream);  // tags -> 0 (never matches)
  hipLaunchKernelGGL(cvt_kernel, dim3((Bn * Tn * In) / (256 * 8)), dim3(256),
                     0, stream, x, xb);
  hipLaunchKernelGGL(cvt_kernel, dim3((In * Hn) / (256 * 8)), dim3(256), 0,
                     stream, fc_w, fwb);
  hipLaunchKernelGGL(lstm_kernel, dim3(NGn * NBLKn), dim3(256), 0, stream, xb,
                     W_ih, W_hh, b_ih, b_hh, hsb, pp);
  hipLaunchKernelGGL(fc_mfma_kernel, dim3((Tn * Bn) / 16), dim3(256), 0,
                     stream, hsb, fwb, fc_b, out);
}

// Round 5
// 2072.368 us; speedup vs baseline: 2.0657x; 2.0657x over previous
//
#include <hip/hip_runtime.h>

#define Tn 512
#define Bn 64
#define In 128
#define Hn 1024
#define GBn 16    // batch rows per group
#define NGn 4     // independent batch groups
#define NBLKn 64  // blocks per group
#define NCOLn 16  // H columns per block

typedef __attribute__((ext_vector_type(8))) short short8;
typedef __attribute__((ext_vector_type(4))) float f32x4;
typedef unsigned long long u64;

__device__ __forceinline__ short f2bf(float f) {
  unsigned u = __builtin_bit_cast(unsigned, f);
  unsigned r = u + 0x7FFFu + ((u >> 16) & 1u);  // RTNE
  return (short)(r >> 16);
}
__device__ __forceinline__ float sigm(float x) { return 1.f / (1.f + __expf(-x)); }
__device__ __forceinline__ float tanh_f(float x) {
  float ax = fabsf(x);
  float e = __expf(-2.f * ax);
  float t = (1.f - e) / (1.f + e);
  return x < 0.f ? -t : t;
}
__device__ __forceinline__ short8 cvt8(const float* p) {
  float4 a0 = *(const float4*)p;
  float4 a1 = *(const float4*)(p + 4);
  short8 w;
  w[0] = f2bf(a0.x); w[1] = f2bf(a0.y); w[2] = f2bf(a0.z); w[3] = f2bf(a0.w);
  w[4] = f2bf(a1.x); w[5] = f2bf(a1.y); w[6] = f2bf(a1.z); w[7] = f2bf(a1.w);
  return w;
}

// f32 -> bf16 bits, 8 per thread. Grid must cover n/8 exactly.
__global__ void __launch_bounds__(256) cvt_kernel(const float* __restrict__ x,
                                                  unsigned short* __restrict__ xb) {
  size_t idx = ((size_t)blockIdx.x * 256 + threadIdx.x) * 8;
  *(short8*)(xb + idx) = cvt8(x + idx);
}

// pp word: (bf16(h) << 16) | tag, tag = t+1 (memset-0 never matches).
// Consumer at step t polls slot (t-1)&1 for tag t. Overwrite safety: every
// block polls the ENTIRE slot, so a producer reaching step t+2 (which
// requires seeing all tag-(t+2) words) proves every block completed its
// step-(t+1) poll, i.e. already consumed the slot it is about to overwrite.
// No fences, no acks, no flags; 4B stores are single-copy atomic.
__global__ void __launch_bounds__(256, 1) lstm_kernel(
    const unsigned short* __restrict__ xb, const float* __restrict__ W_ih,
    const float* __restrict__ W_hh, const float* __restrict__ b_ih,
    const float* __restrict__ b_hh, unsigned short* __restrict__ hsb,
    unsigned* __restrict__ pp) {
  const int bid = blockIdx.x;
  const int grp = bid >> 6;   // batch group 0..3
  const int hc = bid & 63;    // H-chunk 0..63 (16 cols each)
  const int wid = threadIdx.x >> 6;  // wave = gate (i,f,g,o)
  const int lane = threadIdx.x & 63;
  const int rowsel = lane & 15;
  const int k8 = (lane >> 4) * 8;

  __shared__ unsigned short h_lds[GBn * Hn];  // 32 KB staged h (swizzled)
  __shared__ float gates_s[4][16][17];        // padded vs bank conflicts
  __shared__ float bias_s[4][16];

  if (threadIdx.x < 64) {
    int gg = threadIdx.x >> 4, cc = threadIdx.x & 15;
    int idx = gg * Hn + hc * NCOLn + cc;
    bias_s[gg][cc] = b_ih[idx] + b_hh[idx];
  }

  // --- weights -> registers (B-fragments, bf16 bits). One-time. ---
  const int wrow = wid * Hn + hc * NCOLn + rowsel;  // gate row in [0,4096)
  short8 whh[32];
#pragma unroll
  for (int kt = 0; kt < 32; ++kt)
    whh[kt] = cvt8(W_hh + (size_t)wrow * Hn + kt * 32 + k8);
  short8 wih[4];
#pragma unroll
  for (int kt = 0; kt < 4; ++kt)
    wih[kt] = cvt8(W_ih + (size_t)wrow * In + kt * 32 + k8);
  __syncthreads();

  unsigned* ppg = pp + (size_t)grp * 2 * GBn * Hn;
  const unsigned short* xrow = xb + (size_t)(grp * GBn + rowsel) * (Tn * In);

  const int prow = threadIdx.x >> 4;  // pointwise row 0..15
  const int pcol = threadIdx.x & 15;  // H col within chunk
  float c_reg = 0.f;

  // LDS fragment-read base (bytes) + swizzle (matches write layout below)
  const int rswz = (rowsel & 7) << 4;
  const int rbase = rowsel * 2048 + k8 * 2;

#pragma clang loop unroll(disable)
  for (int t = 0; t < Tn; ++t) {
    f32x4 acc[4];
#pragma unroll
    for (int q = 0; q < 4; ++q) acc[q] = (f32x4){0.f, 0.f, 0.f, 0.f};

    // x-part: independent of h, issues before the poll
    {
      const unsigned short* xp = xrow + (size_t)t * In + k8;
#pragma unroll
      for (int kt = 0; kt < 4; ++kt) {
        short8 a = *(const short8*)(xp + kt * 32);
        acc[kt] = __builtin_amdgcn_mfma_f32_16x16x32_bf16(a, wih[kt], acc[kt],
                                                          0, 0, 0);
      }
    }

    if (t > 0) {
      const u64 want2 = (u64)t | ((u64)t << 32);
      const u64* src64 = (const u64*)(ppg + ((t - 1) & 1) * (GBn * Hn));
      // wave covers rows wid*4..wid*4+3; j = row-half index (j>>1 = row
      // within wave, j&1 = which 512-col half). Per half: 16 u64/lane.
#pragma unroll
      for (int half = 0; half < 2; ++half) {
        u64 v[16];
        while (true) {
          bool okv = true;
#pragma unroll
          for (int jj = 0; jj < 4; ++jj) {
            int j = half * 4 + jj;
            int row = wid * 4 + (j >> 1);
            const u64* pl = src64 + row * 512 + (j & 1) * 256 + lane * 4;
#pragma unroll
            for (int q = 0; q < 4; ++q)
              v[jj * 4 + q] = __hip_atomic_load(pl + q, __ATOMIC_RELAXED,
                                                __HIP_MEMORY_SCOPE_AGENT);
          }
#pragma unroll
          for (int j = 0; j < 16; ++j)
            okv = okv && ((v[j] & 0x0000FFFF0000FFFFULL) == want2);
          if (__all(okv)) break;
          __builtin_amdgcn_s_sleep(1);
        }
        // strip tags -> bf16 pairs; write LDS in round-3's layout:
        // consecutive lanes -> consecutive 16B within the row (conflict-free),
        // XOR row-swizzle matching the fragment reads.
#pragma unroll
        for (int jj = 0; jj < 4; ++jj) {
          int j = half * 4 + jj;
          int row = wid * 4 + (j >> 1);
          uint4 w;
          w.x = __builtin_amdgcn_perm((unsigned)(v[jj * 4 + 0] >> 32),
                                      (unsigned)v[jj * 4 + 0], 0x07060302);
          w.y = __builtin_amdgcn_perm((unsigned)(v[jj * 4 + 1] >> 32),
                                      (unsigned)v[jj * 4 + 1], 0x07060302);
          w.z = __builtin_amdgcn_perm((unsigned)(v[jj * 4 + 2] >> 32),
                                      (unsigned)v[jj * 4 + 2], 0x07060302);
          w.w = __builtin_amdgcn_perm((unsigned)(v[jj * 4 + 3] >> 32),
                                      (unsigned)v[jj * 4 + 3], 0x07060302);
          int byteoff = ((wid * 4096 + j * 512 + lane * 8) * 2) ^
                        ((row & 7) << 4);
          *(uint4*)((char*)h_lds + byteoff) = w;
        }
      }
      __syncthreads();  // bar_h: h_lds ready (also isolates prev-iter reads)

      // h-part MFMAs from LDS
#pragma unroll
      for (int kt = 0; kt < 32; ++kt) {
        short8 a = *(const short8*)((char*)h_lds + ((rbase + kt * 64) ^ rswz));
        acc[kt & 3] = __builtin_amdgcn_mfma_f32_16x16x32_bf16(a, whh[kt],
                                                              acc[kt & 3], 0, 0, 0);
      }
    }

    f32x4 asum = (acc[0] + acc[1]) + (acc[2] + acc[3]);
#pragma unroll
    for (int r = 0; r < 4; ++r)
      gates_s[wid][(lane >> 4) * 4 + r][lane & 15] = asum[r];
    __syncthreads();  // bar_g: gates ready (also protects h_lds/gates reuse)

    // pointwise: thread owns (prow, pcol); c stays in a register
    float iv = gates_s[0][prow][pcol] + bias_s[0][pcol];
    float fv = gates_s[1][prow][pcol] + bias_s[1][pcol];
    float gv = gates_s[2][prow][pcol] + bias_s[2][pcol];
    float ov = gates_s[3][prow][pcol] + bias_s[3][pcol];
    float ig = sigm(iv), fg = sigm(fv), og = sigm(ov), gt = tanh_f(gv);
    c_reg = fg * c_reg + ig * gt;
    float hval = og * tanh_f(c_reg);
    unsigned hb = (unsigned)(unsigned short)f2bf(hval);
    // fire-and-forget tagged store: data+tag in one atomic u32
    unsigned tagged = (hb << 16) | (unsigned)(t + 1);
    __hip_atomic_store(ppg + (t & 1) * (GBn * Hn) + prow * Hn + hc * NCOLn + pcol,
                       tagged, __ATOMIC_RELAXED, __HIP_MEMORY_SCOPE_AGENT);
    // hs history (bf16 packed pairs) for the FC pass
    unsigned other = __shfl_xor(hb, 1);
    if ((threadIdx.x & 1) == 0) {
      unsigned packed = hb | (other << 16);
      size_t hsidx =
          ((size_t)t * Bn + grp * GBn + prow) * Hn + hc * NCOLn + pcol;
      *(unsigned*)(hsb + hsidx) = packed;
    }
    // no trailing barrier: bar_h/bar_g already order all LDS reuse; the
    // next poll's vmcnt drain absorbs these stores' ack latency.
  }
}

// out[b][t][i] = hs[row=t*64+b][:] . fcw_b16[i][:] + fcb[i], via MFMA.
__global__ void __launch_bounds__(256) fc_mfma_kernel(
    const unsigned short* __restrict__ hsb, const unsigned short* __restrict__ fwb,
    const float* __restrict__ fcb, float* __restrict__ out) {
  const int wid = threadIdx.x >> 6;
  const int lane = threadIdx.x & 63;
  const int rowsel = lane & 15;
  const int k8 = (lane >> 4) * 8;
  const int r0 = blockIdx.x * 16;
  const int i0 = wid * 32;
  f32x4 acc0 = {0.f, 0.f, 0.f, 0.f}, acc1 = {0.f, 0.f, 0.f, 0.f};
  const unsigned short* hrow = hsb + (size_t)(r0 + rowsel) * Hn + k8;
  const unsigned short* w0 = fwb + (size_t)(i0 + rowsel) * Hn + k8;
  const unsigned short* w1 = w0 + 16 * Hn;
#pragma unroll 8
  for (int kt = 0; kt < 32; ++kt) {
    short8 a = *(const short8*)(hrow + kt * 32);
    short8 b0 = *(const short8*)(w0 + kt * 32);
    short8 b1 = *(const short8*)(w1 + kt * 32);
    acc0 = __builtin_amdgcn_mfma_f32_16x16x32_bf16(a, b0, acc0, 0, 0, 0);
    acc1 = __builtin_amdgcn_mfma_f32_16x16x32_bf16(a, b1, acc1, 0, 0, 0);
  }
  const int n = lane & 15;
  float bias0 = fcb[i0 + n], bias1 = fcb[i0 + 16 + n];
#pragma unroll
  for (int r = 0; r < 4; ++r) {
    int row = r0 + (lane >> 4) * 4 + r;  // row = t*64 + b
    float* op = out + ((size_t)(row & 63) * Tn + (row >> 6)) * In;
    op[i0 + n] = acc0[r] + bias0;
    op[i0 + 16 + n] = acc1[r] + bias1;
  }
}

extern "C" void kernel_launch(void* const* d_in, const int* in_sizes, int n_in,
                              void* d_out, int out_size, void* d_ws,
                              size_t ws_size, hipStream_t stream) {
  const float* x    = (const float*)d_in[0];
  const float* W_ih = (const float*)d_in[1];
  const float* W_hh = (const float*)d_in[2];
  const float* b_ih = (const float*)d_in[3];
  const float* b_hh = (const float*)d_in[4];
  const float* fc_w = (const float*)d_in[5];
  const float* fc_b = (const float*)d_in[6];
  float* out = (float*)d_out;

  const size_t hs_b = (size_t)Tn * Bn * Hn * 2;        // 64 MiB bf16 hs
  const size_t x_b  = (size_t)Bn * Tn * In * 2;        // 8 MiB bf16 x
  const size_t fw_b = (size_t)In * Hn * 2;             // 256 KiB bf16 fc_w
  const size_t pp_b = (size_t)NGn * 2 * GBn * Hn * 4;  // 512 KiB tagged u32

  char* wsc = (char*)d_ws;
  unsigned short* hsb = (unsigned short*)wsc;
  unsigned short* xb  = (unsigned short*)(wsc + hs_b);
  unsigned short* fwb = (unsigned short*)(wsc + hs_b + x_b);
  unsigned* pp = (unsigned*)(wsc + hs_b + x_b + fw_b);

  (void)hipMemsetAsync(pp, 0, pp_b, stream);  // tags -> 0 (never matches)
  hipLaunchKernelGGL(cvt_kernel, dim3((Bn * Tn * In) / (256 * 8)), dim3(256),
                     0, stream, x, xb);
  hipLaunchKernelGGL(cvt_kernel, dim3((In * Hn) / (256 * 8)), dim3(256), 0,
                     stream, fc_w, fwb);
  hipLaunchKernelGGL(lstm_kernel, dim3(NGn * NBLKn), dim3(256), 0, stream, xb,
                     W_ih, W_hh, b_ih, b_hh, hsb, pp);
  hipLaunchKernelGGL(fc_mfma_kernel, dim3((Tn * Bn) / 16), dim3(256), 0,
                     stream, hsb, fwb, fc_b, out);
}

// Round 6
// 1943.338 us; speedup vs baseline: 2.2029x; 1.0664x over previous
//
#include <hip/hip_runtime.h>

#define Tn 512
#define Bn 64
#define In 128
#define Hn 1024
#define GBn 16    // batch rows per group
#define NGn 4     // independent batch groups
#define NBLKn 32  // blocks per group (Hn / NCOLn)
#define NCOLn 32  // H columns per block
#define ROW64 (Hn / 4)  // u64 words per h-row (4 cols packed per u64)

typedef __attribute__((ext_vector_type(8))) short short8;
typedef __attribute__((ext_vector_type(4))) float f32x4;
typedef unsigned long long u64;
typedef unsigned int u32;

__device__ __forceinline__ short f2bf(float f) {
  u32 u = __builtin_bit_cast(u32, f);
  u32 r = u + 0x7FFFu + ((u >> 16) & 1u);  // RTNE
  return (short)(r >> 16);
}
__device__ __forceinline__ float sigm(float x) { return 1.f / (1.f + __expf(-x)); }
__device__ __forceinline__ float tanh_f(float x) {
  float ax = fabsf(x);
  float e = __expf(-2.f * ax);
  float t = (1.f - e) / (1.f + e);
  return x < 0.f ? -t : t;
}
__device__ __forceinline__ short8 cvt8(const float* p) {
  float4 a0 = *(const float4*)p;
  float4 a1 = *(const float4*)(p + 4);
  short8 w;
  w[0] = f2bf(a0.x); w[1] = f2bf(a0.y); w[2] = f2bf(a0.z); w[3] = f2bf(a0.w);
  w[4] = f2bf(a1.x); w[5] = f2bf(a1.y); w[6] = f2bf(a1.z); w[7] = f2bf(a1.w);
  return w;
}

// f32 -> bf16 bits, 8 per thread. Grid must cover n/8 exactly.
__global__ void __launch_bounds__(256) cvt_kernel(const float* __restrict__ x,
                                                  unsigned short* __restrict__ xb) {
  size_t idx = ((size_t)blockIdx.x * 256 + threadIdx.x) * 8;
  *(short8*)(xb + idx) = cvt8(x + idx);
}

// Wire format (per u64, 4 H-cols): lo32 = q0 | q1<<12 ; hi32 = q2 | q3<<12 |
// tag<<24, q = round(h*2048) in [-2048,2047] (12-bit fixed point, step
// 2^-11 <= bf16 ulp for |h|>0.25), tag = (t%255)+1 (8 bits, never 0 =
// memset init; alias needs 510-step skew, impossible: skew <= ~1 step).
// 2-slot ping-pong safety: producer P overwrites slot s at step u+1 only
// after P's step-(u+1) poll saw every consumer C's tag-(u+1) words, which C
// posts only AFTER C finished reading slot s at step u. One atomic u64
// store per 4 cols; no fences, no flags, no acks.
__global__ void __launch_bounds__(512, 2) lstm_kernel(
    const unsigned short* __restrict__ xb, const float* __restrict__ W_ih,
    const float* __restrict__ W_hh, const float* __restrict__ b_ih,
    const float* __restrict__ b_hh, unsigned short* __restrict__ hsb,
    u64* __restrict__ pp) {
  const int bid = blockIdx.x;
  const int grp = bid >> 5;          // batch group 0..3
  const int hc = bid & 31;           // H-chunk 0..31 (32 cols each)
  const int tid = threadIdx.x;
  const int wid = tid >> 6;          // wave 0..7
  const int lane = tid & 63;
  const int rowsel = lane & 15;
  const int k8 = (lane >> 4) * 8;
  const int gate = wid >> 1;         // 0..3 (i,f,g,o)
  const int ct = wid & 1;            // col-tile within chunk

  __shared__ unsigned short h_lds[GBn * Hn];  // 32 KB staged h (swizzled)
  __shared__ float gates_s[4][16][34];        // padded vs bank conflicts
  __shared__ float bias_s[4][NCOLn];

  if (tid < 128) {
    int gg = tid >> 5, cc = tid & 31;
    int idx = gg * Hn + hc * NCOLn + cc;
    bias_s[gg][cc] = b_ih[idx] + b_hh[idx];
  }

  // --- weights -> registers (B-fragments, bf16 bits). One-time. ---
  const int wrow = gate * Hn + hc * NCOLn + ct * 16 + rowsel;
  short8 whh[32];
#pragma unroll
  for (int kt = 0; kt < 32; ++kt)
    whh[kt] = cvt8(W_hh + (size_t)wrow * Hn + kt * 32 + k8);
  short8 wih[4];
#pragma unroll
  for (int kt = 0; kt < 4; ++kt)
    wih[kt] = cvt8(W_ih + (size_t)wrow * In + kt * 32 + k8);
  __syncthreads();

  u64* ppg = pp + (size_t)grp * 2 * (GBn * ROW64);
  const unsigned short* xrow = xb + (size_t)(grp * GBn + rowsel) * (Tn * In);

  const int prow = tid >> 5;  // pointwise row 0..15
  const int pcol = tid & 31;  // pointwise col within chunk
  float c_reg = 0.f;

  // LDS fragment-read base (bytes) + swizzle (matches write layout below)
  const int rswz = (rowsel & 7) << 4;
  const int rbase = rowsel * 2048 + k8 * 2;

#pragma clang loop unroll(disable)
  for (int t = 0; t < Tn; ++t) {
    f32x4 acc[4];
#pragma unroll
    for (int q = 0; q < 4; ++q) acc[q] = (f32x4){0.f, 0.f, 0.f, 0.f};

    // x-part: independent of h, issues before the poll
    {
      const unsigned short* xp = xrow + (size_t)t * In + k8;
#pragma unroll
      for (int kt = 0; kt < 4; ++kt) {
        short8 a = *(const short8*)(xp + kt * 32);
        acc[kt] = __builtin_amdgcn_mfma_f32_16x16x32_bf16(a, wih[kt], acc[kt],
                                                          0, 0, 0);
      }
    }

    if (t > 0) {
      const u32 want = (u32)((t - 1) % 255) + 1;
      const u64* src64 = ppg + ((t - 1) & 1) * (GBn * ROW64);
      // wave wid covers rows 2*wid, 2*wid+1; 8 u64/lane (32 cols)
      u64 v[8];
      while (true) {
        bool okv = true;
#pragma unroll
        for (int j = 0; j < 8; ++j) {
          const u64* pl =
              src64 + (2 * wid + (j >> 2)) * ROW64 + (j & 3) * 64 + lane;
          v[j] = __hip_atomic_load(pl, __ATOMIC_RELAXED,
                                   __HIP_MEMORY_SCOPE_AGENT);
        }
#pragma unroll
        for (int j = 0; j < 8; ++j)
          okv = okv && ((u32)(v[j] >> 56) == want);
        if (__all(okv)) break;
        __builtin_amdgcn_s_sleep(1);
      }
      // unpack 12-bit fixed -> bf16 pairs; write LDS (conflict-free b64,
      // XOR row-swizzle matching the fragment reads)
#pragma unroll
      for (int j = 0; j < 8; ++j) {
        u32 lo = (u32)v[j], hi = (u32)(v[j] >> 32);
        float f0 = (float)(((int)(lo << 20)) >> 20) * 4.8828125e-4f;
        float f1 = (float)(((int)(lo << 8)) >> 20) * 4.8828125e-4f;
        float f2 = (float)(((int)(hi << 20)) >> 20) * 4.8828125e-4f;
        float f3 = (float)(((int)(hi << 8)) >> 20) * 4.8828125e-4f;
        u32 w01, w23;
        asm("v_cvt_pk_bf16_f32 %0, %1, %2" : "=v"(w01) : "v"(f0), "v"(f1));
        asm("v_cvt_pk_bf16_f32 %0, %1, %2" : "=v"(w23) : "v"(f2), "v"(f3));
        int row = 2 * wid + (j >> 2);
        int byteoff = (row * 2048 + ((j & 3) * 64 + lane) * 8) ^
                      ((row & 7) << 4);
        *(u64*)((char*)h_lds + byteoff) = ((u64)w23 << 32) | (u64)w01;
      }
      __syncthreads();  // bar_h: h_lds ready (also isolates prev-iter reads)

      // h-part MFMAs from LDS
#pragma unroll
      for (int kt = 0; kt < 32; ++kt) {
        short8 a = *(const short8*)((char*)h_lds + ((rbase + kt * 64) ^ rswz));
        acc[kt & 3] = __builtin_amdgcn_mfma_f32_16x16x32_bf16(a, whh[kt],
                                                              acc[kt & 3], 0, 0, 0);
      }
    }

    f32x4 asum = (acc[0] + acc[1]) + (acc[2] + acc[3]);
#pragma unroll
    for (int r = 0; r < 4; ++r)
      gates_s[gate][(lane >> 4) * 4 + r][ct * 16 + (lane & 15)] = asum[r];
    __syncthreads();  // bar_g: gates ready (also protects h_lds/gates reuse)

    // pointwise: thread owns (prow, pcol); c stays in a register
    float iv = gates_s[0][prow][pcol] + bias_s[0][pcol];
    float fv = gates_s[1][prow][pcol] + bias_s[1][pcol];
    float gv = gates_s[2][prow][pcol] + bias_s[2][pcol];
    float ov = gates_s[3][prow][pcol] + bias_s[3][pcol];
    float ig = sigm(iv), fg = sigm(fv), og = sigm(ov), gt = tanh_f(gv);
    c_reg = fg * c_reg + ig * gt;
    float hval = og * tanh_f(c_reg);

    // pack 4 cols -> one tagged u64; lanes pcol%4==0 store (fire-and-forget)
    int q12 = (int)rintf(hval * 2048.f);
    q12 = q12 > 2047 ? 2047 : (q12 < -2048 ? -2048 : q12);
    u32 me = (u32)(q12 & 0xFFF) << (12 * (pcol & 1));
    u32 m2 = me | __shfl_xor(me, 1);   // lanes i=0: lo32, i=2: hi32 (no tag)
    u32 mo = __shfl_xor(m2, 2);        // i=0 receives hi32
    u32 tag = (u32)(t % 255) + 1;
    if ((pcol & 3) == 0) {
      u64 wv = ((u64)(mo | (tag << 24)) << 32) | (u64)m2;
      __hip_atomic_store(
          ppg + (t & 1) * (GBn * ROW64) + prow * ROW64 + (hc * NCOLn + pcol) / 4,
          wv, __ATOMIC_RELAXED, __HIP_MEMORY_SCOPE_AGENT);
    }
    // hs history (bf16 packed pairs) for the FC pass
    u32 hb = (u32)(unsigned short)f2bf(hval);
    u32 other = __shfl_xor(hb, 1);
    if (!(tid & 1)) {
      size_t hsidx =
          ((size_t)t * Bn + grp * GBn + prow) * Hn + hc * NCOLn + pcol;
      *(u32*)(hsb + hsidx) = hb | (other << 16);
    }
    // no trailing barrier: bar_h/bar_g order all LDS reuse.
  }
}

// out[b][t][i] = hs[row=t*64+b][:] . fcw_b16[i][:] + fcb[i], via MFMA.
__global__ void __launch_bounds__(256) fc_mfma_kernel(
    const unsigned short* __restrict__ hsb, const unsigned short* __restrict__ fwb,
    const float* __restrict__ fcb, float* __restrict__ out) {
  const int wid = threadIdx.x >> 6;
  const int lane = threadIdx.x & 63;
  const int rowsel = lane & 15;
  const int k8 = (lane >> 4) * 8;
  const int r0 = blockIdx.x * 16;
  const int i0 = wid * 32;
  f32x4 acc0 = {0.f, 0.f, 0.f, 0.f}, acc1 = {0.f, 0.f, 0.f, 0.f};
  const unsigned short* hrow = hsb + (size_t)(r0 + rowsel) * Hn + k8;
  const unsigned short* w0 = fwb + (size_t)(i0 + rowsel) * Hn + k8;
  const unsigned short* w1 = w0 + 16 * Hn;
#pragma unroll 8
  for (int kt = 0; kt < 32; ++kt) {
    short8 a = *(const short8*)(hrow + kt * 32);
    short8 b0 = *(const short8*)(w0 + kt * 32);
    short8 b1 = *(const short8*)(w1 + kt * 32);
    acc0 = __builtin_amdgcn_mfma_f32_16x16x32_bf16(a, b0, acc0, 0, 0, 0);
    acc1 = __builtin_amdgcn_mfma_f32_16x16x32_bf16(a, b1, acc1, 0, 0, 0);
  }
  const int n = lane & 15;
  float bias0 = fcb[i0 + n], bias1 = fcb[i0 + 16 + n];
#pragma unroll
  for (int r = 0; r < 4; ++r) {
    int row = r0 + (lane >> 4) * 4 + r;  // row = t*64 + b
    float* op = out + ((size_t)(row & 63) * Tn + (row >> 6)) * In;
    op[i0 + n] = acc0[r] + bias0;
    op[i0 + 16 + n] = acc1[r] + bias1;
  }
}

extern "C" void kernel_launch(void* const* d_in, const int* in_sizes, int n_in,
                              void* d_out, int out_size, void* d_ws,
                              size_t ws_size, hipStream_t stream) {
  const float* x    = (const float*)d_in[0];
  const float* W_ih = (const float*)d_in[1];
  const float* W_hh = (const float*)d_in[2];
  const float* b_ih = (const float*)d_in[3];
  const float* b_hh = (const float*)d_in[4];
  const float* fc_w = (const float*)d_in[5];
  const float* fc_b = (const float*)d_in[6];
  float* out = (float*)d_out;

  const size_t hs_b = (size_t)Tn * Bn * Hn * 2;           // 64 MiB bf16 hs
  const size_t x_b  = (size_t)Bn * Tn * In * 2;           // 8 MiB bf16 x
  const size_t fw_b = (size_t)In * Hn * 2;                // 256 KiB bf16 fc_w
  const size_t pp_b = (size_t)NGn * 2 * GBn * ROW64 * 8;  // 256 KiB packed u64

  char* wsc = (char*)d_ws;
  unsigned short* hsb = (unsigned short*)wsc;
  unsigned short* xb  = (unsigned short*)(wsc + hs_b);
  unsigned short* fwb = (unsigned short*)(wsc + hs_b + x_b);
  u64* pp = (u64*)(wsc + hs_b + x_b + fw_b);

  (void)hipMemsetAsync(pp, 0, pp_b, stream);  // tags -> 0 (never matches)
  hipLaunchKernelGGL(cvt_kernel, dim3((Bn * Tn * In) / (256 * 8)), dim3(256),
                     0, stream, x, xb);
  hipLaunchKernelGGL(cvt_kernel, dim3((In * Hn) / (256 * 8)), dim3(256), 0,
                     stream, fc_w, fwb);
  hipLaunchKernelGGL(lstm_kernel, dim3(NGn * NBLKn), dim3(512), 0, stream, xb,
                     W_ih, W_hh, b_ih, b_hh, hsb, pp);
  hipLaunchKernelGGL(fc_mfma_kernel, dim3((Tn * Bn) / 16), dim3(256), 0,
                     stream, hsb, fwb, fc_b, out);
}

// Round 9
// 1603.061 us; speedup vs baseline: 2.6705x; 1.2123x over previous
//
#include <hip/hip_runtime.h>

#define Tn 512
#define Bn 64
#define In 128
#define Hn 1024
#define GBn 16    // batch rows per group
#define NGn 4     // independent batch groups
#define NBLKn 64  // blocks per group (Hn / NCOLn)
#define NCOLn 16  // H columns per block
#define ROW64 (Hn / 4)  // u64 words per h-row (4 cols packed per u64)

typedef __attribute__((ext_vector_type(8))) short short8;
typedef __attribute__((ext_vector_type(4))) float f32x4;
typedef unsigned long long u64;
typedef unsigned int u32;

__device__ __forceinline__ short f2bf(float f) {
  u32 u = __builtin_bit_cast(u32, f);
  u32 r = u + 0x7FFFu + ((u >> 16) & 1u);  // RTNE
  return (short)(r >> 16);
}
__device__ __forceinline__ float sigm(float x) { return 1.f / (1.f + __expf(-x)); }
__device__ __forceinline__ float tanh_f(float x) {
  float ax = fabsf(x);
  float e = __expf(-2.f * ax);
  float t = (1.f - e) / (1.f + e);
  return x < 0.f ? -t : t;
}
__device__ __forceinline__ short8 cvt8(const float* p) {
  float4 a0 = *(const float4*)p;
  float4 a1 = *(const float4*)(p + 4);
  short8 w;
  w[0] = f2bf(a0.x); w[1] = f2bf(a0.y); w[2] = f2bf(a0.z); w[3] = f2bf(a0.w);
  w[4] = f2bf(a1.x); w[5] = f2bf(a1.y); w[6] = f2bf(a1.z); w[7] = f2bf(a1.w);
  return w;
}

// f32 -> bf16 bits, 8 per thread. Grid must cover n/8 exactly.
__global__ void __launch_bounds__(256) cvt_kernel(const float* __restrict__ x,
                                                  unsigned short* __restrict__ xb) {
  size_t idx = ((size_t)blockIdx.x * 256 + threadIdx.x) * 8;
  *(short8*)(xb + idx) = cvt8(x + idx);
}

// Wire: u64 = q0|q1<<12 (lo32), q2|q3<<12|tag<<24 (hi32); q = round(h*2048)
// 12-bit fixed point; tag = (t%255)+1 (never 0 = memset; alias needs 510-step
// skew, impossible at <=1-step skew). 2-slot ping-pong, fire-and-forget
// atomic u64 stores, consumers poll-the-data (full slot). Overwrite safety:
// producer stores tag-(t+2) to slot s only after its step-(t+2) poll saw all
// tag-(t+1) words, which each consumer posts only after finishing its
// step-(t+1) reads of slot s (the store's data depends on those reads).
// ROUND-8 BUG (fixed here): the x A-fragment loads omitted the +k8 lane
// offset (A[m][k], k=(lane>>4)*8+j) -> wrong x columns in 3/4 of K-slices.
__global__ void __launch_bounds__(256, 1) lstm_kernel(
    const unsigned short* __restrict__ xb, const float* __restrict__ W_ih,
    const float* __restrict__ W_hh, const float* __restrict__ b_ih,
    const float* __restrict__ b_hh, unsigned short* __restrict__ hsb,
    u64* __restrict__ pp) {
  const int bid = blockIdx.x;
  const int grp = bid >> 6;   // batch group 0..3
  const int hc = bid & 63;    // H-chunk (16 cols each)
  const int tid = threadIdx.x;
  const int wid = tid >> 6;   // wave = gate (i,f,g,o)
  const int lane = tid & 63;
  const int rowsel = lane & 15;
  const int k8 = (lane >> 4) * 8;

  __shared__ unsigned short h_lds[GBn * Hn];  // 32 KB staged h (swizzled)
  __shared__ float gates_s[4][16][17];
  __shared__ float bias_s[4][16];

  if (tid < 64) {
    int gg = tid >> 4, cc = tid & 15;
    int idx = gg * Hn + hc * NCOLn + cc;
    bias_s[gg][cc] = b_ih[idx] + b_hh[idx];
  }

  // --- weights -> registers (B-fragments, bf16 bits). One-time. ---
  const int wrow = wid * Hn + hc * NCOLn + rowsel;
  short8 whh[32];
#pragma unroll
  for (int kt = 0; kt < 32; ++kt)
    whh[kt] = cvt8(W_hh + (size_t)wrow * Hn + kt * 32 + k8);
  short8 wih[4];
#pragma unroll
  for (int kt = 0; kt < 4; ++kt)
    wih[kt] = cvt8(W_ih + (size_t)wrow * In + kt * 32 + k8);
  __syncthreads();

  u64* ppg = pp + (size_t)grp * 2 * (GBn * ROW64);
  const unsigned short* xrow = xb + (size_t)(grp * GBn + rowsel) * (Tn * In);

  const int prow = tid >> 4;  // pointwise row 0..15
  const int pcol = tid & 15;  // pointwise col within chunk
  float c_reg = 0.f;

  const int rswz = (rowsel & 7) << 4;
  const int rbase = rowsel * 2048 + k8 * 2;

  // x fragments prefetched one step ahead: the x-MFMAs at loop top are
  // register-only, decoupled from this step's store acks / poll.
  short8 xa[4], xn[4];
#pragma unroll
  for (int kt = 0; kt < 4; ++kt)
    xa[kt] = *(const short8*)(xrow + k8 + kt * 32);  // FIX: +k8

#pragma clang loop unroll(disable)
  for (int t = 0; t < Tn; ++t) {
    f32x4 acc[4];
#pragma unroll
    for (int q = 0; q < 4; ++q) acc[q] = (f32x4){0.f, 0.f, 0.f, 0.f};

    // x-part: register-only
#pragma unroll
    for (int kt = 0; kt < 4; ++kt)
      acc[kt] = __builtin_amdgcn_mfma_f32_16x16x32_bf16(xa[kt], wih[kt],
                                                        acc[kt], 0, 0, 0);
    // prefetch x for t+1
    {
      int tn = (t + 1 < Tn) ? t + 1 : t;
      const unsigned short* xp = xrow + (size_t)tn * In + k8;  // FIX: +k8
#pragma unroll
      for (int kt = 0; kt < 4; ++kt) xn[kt] = *(const short8*)(xp + kt * 32);
    }

    if (t > 0) {
      const u32 want = (u32)((t - 1) % 255) + 1;
      const u64* src64 = ppg + ((t - 1) & 1) * (GBn * ROW64);
      // wave wid covers rows 4*wid..4*wid+3; 16 u64/lane = full 4 rows
      u64 v[16];
      while (true) {
        bool okv = true;
#pragma unroll
        for (int j = 0; j < 16; ++j) {
          const u64* pl =
              src64 + (4 * wid + (j >> 2)) * ROW64 + (j & 3) * 64 + lane;
          v[j] = __hip_atomic_load(pl, __ATOMIC_RELAXED,
                                   __HIP_MEMORY_SCOPE_AGENT);
        }
#pragma unroll
        for (int j = 0; j < 16; ++j) okv = okv && ((u32)(v[j] >> 56) == want);
        if (__all(okv)) break;
        __builtin_amdgcn_s_sleep(1);
      }
      // unpack 12-bit fixed -> bf16 pairs; LDS write conflict-free b64,
      // XOR row-swizzle matching the fragment reads
#pragma unroll
      for (int j = 0; j < 16; ++j) {
        u32 lo = (u32)v[j], hi = (u32)(v[j] >> 32);
        float f0 = (float)(((int)(lo << 20)) >> 20) * 4.8828125e-4f;
        float f1 = (float)(((int)(lo << 8)) >> 20) * 4.8828125e-4f;
        float f2 = (float)(((int)(hi << 20)) >> 20) * 4.8828125e-4f;
        float f3 = (float)(((int)(hi << 8)) >> 20) * 4.8828125e-4f;
        u32 w01, w23;
        asm("v_cvt_pk_bf16_f32 %0, %1, %2" : "=v"(w01) : "v"(f0), "v"(f1));
        asm("v_cvt_pk_bf16_f32 %0, %1, %2" : "=v"(w23) : "v"(f2), "v"(f3));
        int row = 4 * wid + (j >> 2);
        int c4 = (j & 3) * 64 + lane;
        int byteoff = (row * 2048 + c4 * 8) ^ ((row & 7) << 4);
        *(u64*)((char*)h_lds + byteoff) = ((u64)w23 << 32) | (u64)w01;
      }
      __syncthreads();  // bar_h: h_lds ready

      // h-part MFMAs from LDS
#pragma unroll
      for (int kt = 0; kt < 32; ++kt) {
        short8 a = *(const short8*)((char*)h_lds + ((rbase + kt * 64) ^ rswz));
        acc[kt & 3] = __builtin_amdgcn_mfma_f32_16x16x32_bf16(a, whh[kt],
                                                              acc[kt & 3], 0, 0, 0);
      }
    }

    f32x4 asum = (acc[0] + acc[1]) + (acc[2] + acc[3]);
#pragma unroll
    for (int r = 0; r < 4; ++r)
      gates_s[wid][(lane >> 4) * 4 + r][lane & 15] = asum[r];
    __syncthreads();  // bar_g: gates ready (also protects h_lds reuse)

    // pointwise: thread owns (prow, pcol); c stays in a register
    float iv = gates_s[0][prow][pcol] + bias_s[0][pcol];
    float fv = gates_s[1][prow][pcol] + bias_s[1][pcol];
    float gv = gates_s[2][prow][pcol] + bias_s[2][pcol];
    float ov = gates_s[3][prow][pcol] + bias_s[3][pcol];
    float ig = sigm(iv), fg = sigm(fv), og = sigm(ov), gt = tanh_f(gv);
    c_reg = fg * c_reg + ig * gt;
    float hval = og * tanh_f(c_reg);

    // pack 4 cols -> one tagged u64; lanes pcol%4==0 store (fire-and-forget)
    int q12 = (int)rintf(hval * 2048.f);
    q12 = q12 > 2047 ? 2047 : (q12 < -2048 ? -2048 : q12);
    u32 me = (u32)(q12 & 0xFFF) << (12 * (pcol & 1));
    u32 m2 = me | __shfl_xor(me, 1);
    u32 mo = __shfl_xor(m2, 2);
    u32 tag = (u32)(t % 255) + 1;
    if ((pcol & 3) == 0) {
      u64 wv = ((u64)(mo | (tag << 24)) << 32) | (u64)m2;
      __hip_atomic_store(
          ppg + (t & 1) * (GBn * ROW64) + prow * ROW64 + ((hc * NCOLn + pcol) >> 2),
          wv, __ATOMIC_RELAXED, __HIP_MEMORY_SCOPE_AGENT);
    }
    // hs history (bf16 packed pairs) for the FC pass
    u32 hb = (u32)(unsigned short)f2bf(hval);
    u32 other = __shfl_xor(hb, 1);
    if (!(tid & 1)) {
      size_t hsidx =
          ((size_t)t * Bn + grp * GBn + prow) * Hn + hc * NCOLn + pcol;
      *(u32*)(hsb + hsidx) = hb | (other << 16);
    }

#pragma unroll
    for (int kt = 0; kt < 4; ++kt) xa[kt] = xn[kt];
  }
}

// out[b][t][i] = hs[row=t*64+b][:] . fcw_b16[i][:] + fcb[i], via MFMA.
__global__ void __launch_bounds__(256) fc_mfma_kernel(
    const unsigned short* __restrict__ hsb, const unsigned short* __restrict__ fwb,
    const float* __restrict__ fcb, float* __restrict__ out) {
  const int wid = threadIdx.x >> 6;
  const int lane = threadIdx.x & 63;
  const int rowsel = lane & 15;
  const int k8 = (lane >> 4) * 8;
  const int r0 = blockIdx.x * 16;
  const int i0 = wid * 32;
  f32x4 acc0 = {0.f, 0.f, 0.f, 0.f}, acc1 = {0.f, 0.f, 0.f, 0.f};
  const unsigned short* hrow = hsb + (size_t)(r0 + rowsel) * Hn + k8;
  const unsigned short* w0 = fwb + (size_t)(i0 + rowsel) * Hn + k8;
  const unsigned short* w1 = w0 + 16 * Hn;
#pragma unroll 8
  for (int kt = 0; kt < 32; ++kt) {
    short8 a = *(const short8*)(hrow + kt * 32);
    short8 b0 = *(const short8*)(w0 + kt * 32);
    short8 b1 = *(const short8*)(w1 + kt * 32);
    acc0 = __builtin_amdgcn_mfma_f32_16x16x32_bf16(a, b0, acc0, 0, 0, 0);
    acc1 = __builtin_amdgcn_mfma_f32_16x16x32_bf16(a, b1, acc1, 0, 0, 0);
  }
  const int n = lane & 15;
  float bias0 = fcb[i0 + n], bias1 = fcb[i0 + 16 + n];
#pragma unroll
  for (int r = 0; r < 4; ++r) {
    int row = r0 + (lane >> 4) * 4 + r;  // row = t*64 + b
    float* op = out + ((size_t)(row & 63) * Tn + (row >> 6)) * In;
    op[i0 + n] = acc0[r] + bias0;
    op[i0 + 16 + n] = acc1[r] + bias1;
  }
}

extern "C" void kernel_launch(void* const* d_in, const int* in_sizes, int n_in,
                              void* d_out, int out_size, void* d_ws,
                              size_t ws_size, hipStream_t stream) {
  const float* x    = (const float*)d_in[0];
  const float* W_ih = (const float*)d_in[1];
  const float* W_hh = (const float*)d_in[2];
  const float* b_ih = (const float*)d_in[3];
  const float* b_hh = (const float*)d_in[4];
  const float* fc_w = (const float*)d_in[5];
  const float* fc_b = (const float*)d_in[6];
  float* out = (float*)d_out;

  const size_t hs_b = (size_t)Tn * Bn * Hn * 2;           // 64 MiB bf16 hs
  const size_t x_b  = (size_t)Bn * Tn * In * 2;           // 8 MiB bf16 x
  const size_t fw_b = (size_t)In * Hn * 2;                // 256 KiB bf16 fc_w
  const size_t pp_b = (size_t)NGn * 2 * GBn * ROW64 * 8;  // 256 KiB packed u64

  char* wsc = (char*)d_ws;
  unsigned short* hsb = (unsigned short*)wsc;
  unsigned short* xb  = (unsigned short*)(wsc + hs_b);
  unsigned short* fwb = (unsigned short*)(wsc + hs_b + x_b);
  u64* pp = (u64*)(wsc + hs_b + x_b + fw_b);

  (void)hipMemsetAsync(pp, 0, pp_b, stream);  // tags -> 0 (never matches)
  hipLaunchKernelGGL(cvt_kernel, dim3((Bn * Tn * In) / (256 * 8)), dim3(256),
                     0, stream, x, xb);
  hipLaunchKernelGGL(cvt_kernel, dim3((In * Hn) / (256 * 8)), dim3(256), 0,
                     stream, fc_w, fwb);
  hipLaunchKernelGGL(lstm_kernel, dim3(NGn * NBLKn), dim3(256), 0, stream, xb,
                     W_ih, W_hh, b_ih, b_hh, hsb, pp);
  hipLaunchKernelGGL(fc_mfma_kernel, dim3((Tn * Bn) / 16), dim3(256), 0,
                     stream, hsb, fwb, fc_b, out);
}